// Round 3
// baseline (107.038 us; speedup 1.0000x reference)
//
#include <hip/hip_runtime.h>
#include <stdint.h>

#define NB 8
#define NT 2048
#define NC 1024
#define HD 64

typedef __attribute__((ext_vector_type(8)))  short s16x8;
typedef __attribute__((ext_vector_type(4)))  float f32x4;
typedef __attribute__((ext_vector_type(16))) float f32x16;

__device__ inline ushort f2b(float f) {
    union { float f; uint32_t u; } c; c.f = f;
    uint32_t u = c.u;
    uint32_t r = (u + 0x7fffu + ((u >> 16) & 1u)) >> 16;   // RNE, finite inputs
    return (ushort)r;
}

__device__ inline uint32_t cvt_pk_bf16(float lo, float hi) {
    uint32_t r;
    asm("v_cvt_pk_bf16_f32 %0, %1, %2" : "=v"(r) : "v"(lo), "v"(hi));
    return r;
}

// ---------------------------------------------------------------------------
// Kernel 0: W [1024][192] f32  ->  Wt [192][1024] bf16, q-cols pre-scaled by
// 0.125 * log2(e) so attention logits are already base-2.
// ---------------------------------------------------------------------------
__global__ __launch_bounds__(256) void wprep(const float* __restrict__ W,
                                             ushort* __restrict__ wt) {
    int tid = blockIdx.x * 256 + threadIdx.x;   // 192*1024 total
    int n = tid >> 10;          // 0..191 (output col of qkv)
    int k = tid & 1023;         // 0..1023
    float v = W[k * 192 + n];
    if (n < 64) v *= 0.125f * 1.4426950408889634f;
    wt[n * 1024 + k] = f2b(v);
}

// ---------------------------------------------------------------------------
// Kernel 1: qkv = x @ W.  Zero-LDS, zero-barrier register streaming.
// 4 waves/block; each wave owns 16 rows x all 192 cols (12 accum frags).
// A-frags: per-lane loads from x (f32 -> cvt_pk bf16).  B-frags: per-lane
// loads from wt (L2/L1-resident, 4 waves/block hit identical addresses).
// Fully unrolled K-loop: every global offset fits the 13-bit imm -> zero
// address arithmetic in the loop; 2-deep ping-pong prefetch keeps ~16 KB/CU
// of x in flight (HBM latency covered); no barriers -> no vmcnt(0) drain.
// ---------------------------------------------------------------------------
__global__ __launch_bounds__(256, 1) void qkv_gemm(const float* __restrict__ x,
                                                   const ushort* __restrict__ wt,
                                                   ushort* __restrict__ qs,
                                                   ushort* __restrict__ kk,
                                                   ushort* __restrict__ vt) {
    const int tid = threadIdx.x;
    const int wv  = tid >> 6;
    const int ln  = tid & 63;
    const int r16 = ln & 15;
    const int hi4 = ln >> 4;          // 0..3
    const int row0 = blockIdx.x * 64;
    const int myrow = row0 + wv * 16 + r16;

    const float* xp = x + (size_t)myrow * NC + hi4 * 8;
    const ushort* wp[12];
#pragma unroll
    for (int nf = 0; nf < 12; ++nf)
        wp[nf] = wt + (size_t)(nf * 16 + r16) * 1024 + hi4 * 8;

    f32x4 acc[12];
#pragma unroll
    for (int i = 0; i < 12; ++i)
#pragma unroll
        for (int e = 0; e < 4; ++e) acc[i][e] = 0.f;

    // --- prologue: prefetch steps 0 and 1 ---
    float4 xA0 = *(const float4*)(xp);
    float4 xA1 = *(const float4*)(xp + 4);
    float4 xB0 = *(const float4*)(xp + 32);
    float4 xB1 = *(const float4*)(xp + 36);
    s16x8 wA[12], wB[12];
#pragma unroll
    for (int nf = 0; nf < 12; ++nf) wA[nf] = *(const s16x8*)(wp[nf]);
#pragma unroll
    for (int nf = 0; nf < 12; ++nf) wB[nf] = *(const s16x8*)(wp[nf] + 32);

#pragma unroll
    for (int t = 0; t < 32; t += 2) {
        // ---- even step t: consume A set, prefetch t+2 into A set ----
        {
            union { uint32_t w[4]; s16x8 v; } pk;
            pk.w[0] = cvt_pk_bf16(xA0.x, xA0.y);
            pk.w[1] = cvt_pk_bf16(xA0.z, xA0.w);
            pk.w[2] = cvt_pk_bf16(xA1.x, xA1.y);
            pk.w[3] = cvt_pk_bf16(xA1.z, xA1.w);
            s16x8 a = pk.v;
            if (t + 2 < 32) {
                xA0 = *(const float4*)(xp + (t + 2) * 32);
                xA1 = *(const float4*)(xp + (t + 2) * 32 + 4);
            }
#pragma unroll
            for (int nf = 0; nf < 12; ++nf)
                acc[nf] = __builtin_amdgcn_mfma_f32_16x16x32_bf16(a, wA[nf], acc[nf], 0, 0, 0);
            if (t + 2 < 32) {
#pragma unroll
                for (int nf = 0; nf < 12; ++nf)
                    wA[nf] = *(const s16x8*)(wp[nf] + (t + 2) * 32);
            }
        }
        // ---- odd step t+1: consume B set, prefetch t+3 into B set ----
        {
            union { uint32_t w[4]; s16x8 v; } pk;
            pk.w[0] = cvt_pk_bf16(xB0.x, xB0.y);
            pk.w[1] = cvt_pk_bf16(xB0.z, xB0.w);
            pk.w[2] = cvt_pk_bf16(xB1.x, xB1.y);
            pk.w[3] = cvt_pk_bf16(xB1.z, xB1.w);
            s16x8 a = pk.v;
            if (t + 3 < 32) {
                xB0 = *(const float4*)(xp + (t + 3) * 32);
                xB1 = *(const float4*)(xp + (t + 3) * 32 + 4);
            }
#pragma unroll
            for (int nf = 0; nf < 12; ++nf)
                acc[nf] = __builtin_amdgcn_mfma_f32_16x16x32_bf16(a, wB[nf], acc[nf], 0, 0, 0);
            if (t + 3 < 32) {
#pragma unroll
                for (int nf = 0; nf < 12; ++nf)
                    wB[nf] = *(const s16x8*)(wp[nf] + (t + 3) * 32);
            }
        }
    }

    // --- epilogue: scatter to qs / kk / vt(bf16, transposed) ---
    // C-frag: col = r16 (within 16-col frag), row = hi4*4 + j (within wave's 16 rows)
    const int b = row0 >> 11;
    const int rbase = row0 + wv * 16 + hi4 * 4;
#pragma unroll
    for (int nf = 0; nf < 12; ++nf) {
        int colg = nf * 16 + r16;          // 0..191
        f32x4 v = acc[nf];
        if (nf < 4) {
#pragma unroll
            for (int j = 0; j < 4; ++j)
                qs[(size_t)(rbase + j) * HD + colg] = f2b(v[j]);
        } else if (nf < 8) {
#pragma unroll
            for (int j = 0; j < 4; ++j)
                kk[(size_t)(rbase + j) * HD + (colg - 64)] = f2b(v[j]);
        } else {
            int d = colg - 128;
            union { ushort4 s; ushort u[4]; } pk;
#pragma unroll
            for (int j = 0; j < 4; ++j) pk.u[j] = f2b(v[j]);
            *(ushort4*)(&vt[((size_t)(b * 64 + d)) * NT + (rbase & (NT - 1))]) = pk.s;
        }
    }
}

// ---------------------------------------------------------------------------
// Kernel 2: causal flash attention. 4 waves/block, intra-block split-K:
// wave w handles k-tiles w, w+4, ... of its 32-row q-tile; partial
// (m,l,o) merged in LDS with exp2 rescaling. grid = 512, big tiles first.
// ---------------------------------------------------------------------------
__global__ __launch_bounds__(256) void attn(const ushort* __restrict__ qs,
                                            const ushort* __restrict__ kk,
                                            const ushort* __restrict__ vt,
                                            float* __restrict__ out) {
    __shared__ float ob[4][64][33];   // per-wave unnormalized O^T partials
    __shared__ float ml[4][2][32];    // per-wave m / lsum per q col

    const int bid  = blockIdx.x;
    const int b    = bid & 7;
    const int tile = 63 - (bid >> 3);          // big-first for balance
    const int tid  = threadIdx.x;
    const int wv   = tid >> 6;                 // 0..3  (k-split index)
    const int l    = tid & 63;
    const int qcol = l & 31;
    const int hi   = l >> 5;
    const int r0   = tile * 32;

    const ushort* qb = qs + ((size_t)(b * NT + r0)) * HD;
    const ushort* kb = kk + (size_t)b * NT * HD;
    const ushort* vb = vt + (size_t)b * HD * NT;

    s16x8 qf[4];
#pragma unroll
    for (int c = 0; c < 4; ++c)
        qf[c] = *(const s16x8*)(qb + (size_t)qcol * HD + c * 16 + hi * 8);

    f32x16 o0, o1;
#pragma unroll
    for (int i = 0; i < 16; ++i) { o0[i] = 0.f; o1[i] = 0.f; }
    float m = -3.0e30f, lsum = 0.f;

    if (wv <= tile) {
        s16x8 kf[4], vf[4];
        {
            const ushort* kr = kb + (size_t)(wv * 32 + qcol) * HD;
#pragma unroll
            for (int c = 0; c < 4; ++c)
                kf[c] = *(const s16x8*)(kr + c * 16 + hi * 8);
#pragma unroll
            for (int dt = 0; dt < 2; ++dt)
#pragma unroll
                for (int kc = 0; kc < 2; ++kc)
                    vf[dt * 2 + kc] = *(const s16x8*)(vb + (size_t)(dt * 32 + qcol) * NT
                                                      + wv * 32 + kc * 16 + hi * 8);
        }

        for (int kt = wv; kt <= tile; kt += 4) {
            // S^T = K . Q^T   (col = q, row-regs = k_local)
            f32x16 s;
#pragma unroll
            for (int i = 0; i < 16; ++i) s[i] = 0.f;
#pragma unroll
            for (int c = 0; c < 4; ++c)
                s = __builtin_amdgcn_mfma_f32_32x32x16_bf16(kf[c], qf[c], s, 0, 0, 0);

            // prefetch this wave's next K/V tiles (stride 4)
            s16x8 kfn[4], vfn[4];
            const bool more = (kt + 4 <= tile);
            if (more) {
                const ushort* kr = kb + (size_t)((kt + 4) * 32 + qcol) * HD;
#pragma unroll
                for (int c = 0; c < 4; ++c)
                    kfn[c] = *(const s16x8*)(kr + c * 16 + hi * 8);
#pragma unroll
                for (int dt = 0; dt < 2; ++dt)
#pragma unroll
                    for (int kc = 0; kc < 2; ++kc)
                        vfn[dt * 2 + kc] = *(const s16x8*)(vb + (size_t)(dt * 32 + qcol) * NT
                                                           + (kt + 4) * 32 + kc * 16 + hi * 8);
            }

            // online softmax (per-lane scalar state: one q per lane)
            const bool diag = (kt == tile);
            float p[16];
#pragma unroll
            for (int r = 0; r < 16; ++r) {
                int klocal = (r & 3) + 8 * (r >> 2) + 4 * hi;
                float sv = s[r];
                if (diag && klocal > qcol) sv = -3.0e30f;
                p[r] = sv;
            }
            float pmax = p[0];
#pragma unroll
            for (int r = 1; r < 16; ++r) pmax = fmaxf(pmax, p[r]);
            pmax = fmaxf(pmax, __shfl_xor(pmax, 32));
            float mnew = fmaxf(m, pmax);
            float corr = exp2f(m - mnew);
            m = mnew;
            float rs = 0.f;
#pragma unroll
            for (int r = 0; r < 16; ++r) { p[r] = exp2f(p[r] - mnew); rs += p[r]; }
            rs += __shfl_xor(rs, 32);
            lsum = lsum * corr + rs;
#pragma unroll
            for (int i = 0; i < 16; ++i) { o0[i] *= corr; o1[i] *= corr; }

            // P (f32, S^T layout) -> bf16 B-fragments via cvt_pk + lane^32 exchange
#pragma unroll
            for (int kc = 0; kc < 2; ++kc) {
                int pb = kc * 8;
                uint32_t a0 = cvt_pk_bf16(p[pb + 0], p[pb + 1]);
                uint32_t a1 = cvt_pk_bf16(p[pb + 2], p[pb + 3]);
                uint32_t b0 = cvt_pk_bf16(p[pb + 4], p[pb + 5]);
                uint32_t b1 = cvt_pk_bf16(p[pb + 6], p[pb + 7]);
                uint32_t a0x = __shfl_xor(a0, 32);
                uint32_t a1x = __shfl_xor(a1, 32);
                uint32_t b0x = __shfl_xor(b0, 32);
                uint32_t b1x = __shfl_xor(b1, 32);
                union { uint32_t w[4]; s16x8 v; } frag;
                frag.w[0] = hi ? b0x : a0;
                frag.w[1] = hi ? b1x : a1;
                frag.w[2] = hi ? b0  : a0x;
                frag.w[3] = hi ? b1  : a1x;
                o0 = __builtin_amdgcn_mfma_f32_32x32x16_bf16(vf[0 * 2 + kc], frag.v, o0, 0, 0, 0);
                o1 = __builtin_amdgcn_mfma_f32_32x32x16_bf16(vf[1 * 2 + kc], frag.v, o1, 0, 0, 0);
            }

            if (more) {
#pragma unroll
                for (int c = 0; c < 4; ++c) kf[c] = kfn[c];
#pragma unroll
                for (int c = 0; c < 4; ++c) vf[c] = vfn[c];
            }
        }
    }

    // --- write per-wave partials (unnormalized) ---
#pragma unroll
    for (int r = 0; r < 16; ++r) {
        int d = (r & 3) + 8 * (r >> 2) + 4 * hi;
        ob[wv][d][qcol]      = o0[r];
        ob[wv][d + 32][qcol] = o1[r];
    }
    if (hi == 0) {
        ml[wv][0][qcol] = m;
        ml[wv][1][qcol] = lsum;
    }
    __syncthreads();

    // --- merge 4 partials + coalesced f32 store ---
    // thread -> (q = tid>>3, d block of 8 at (tid&7)*8)
    const int q  = tid >> 3;
    const int j0 = (tid & 7) * 8;
    float mw[4];
#pragma unroll
    for (int w = 0; w < 4; ++w) mw[w] = ml[w][0][q];
    float M = fmaxf(fmaxf(mw[0], mw[1]), fmaxf(mw[2], mw[3]));
    float sw[4]; float L = 0.f;
#pragma unroll
    for (int w = 0; w < 4; ++w) {
        sw[w] = exp2f(mw[w] - M);
        L += sw[w] * ml[w][1][q];
    }
    float invL = 1.0f / L;
    float vals[8];
#pragma unroll
    for (int j = 0; j < 8; ++j) {
        int d = j0 + j;
        float acc = 0.f;
#pragma unroll
        for (int w = 0; w < 4; ++w) acc += sw[w] * ob[w][d][q];
        vals[j] = acc * invL;
    }
    float* orow = out + ((size_t)(b * NT + r0 + q)) * HD + j0;
    *(float4*)(orow)     = make_float4(vals[0], vals[1], vals[2], vals[3]);
    *(float4*)(orow + 4) = make_float4(vals[4], vals[5], vals[6], vals[7]);
}

// ---------------------------------------------------------------------------
extern "C" void kernel_launch(void* const* d_in, const int* in_sizes, int n_in,
                              void* d_out, int out_size, void* d_ws, size_t ws_size,
                              hipStream_t stream) {
    const float* x = (const float*)d_in[0];
    const float* W = (const float*)d_in[1];
    float* out = (float*)d_out;

    ushort* qs = (ushort*)d_ws;                 // [8][2048][64] bf16 (pre-scaled q)
    ushort* kk = qs + (size_t)NB * NT * HD;     // [8][2048][64]
    ushort* vt = kk + (size_t)NB * NT * HD;     // [8][64][2048]  (V transposed)
    ushort* wt = vt + (size_t)NB * NT * HD;     // [192][1024]    (W^T bf16)

    wprep<<<768, 256, 0, stream>>>(W, wt);
    qkv_gemm<<<256, 256, 0, stream>>>(x, wt, qs, kk, vt);
    attn<<<512, 256, 0, stream>>>(qs, kk, vt, out);
}

// Round 4
// 58.497 us; speedup vs baseline: 1.8298x; 1.8298x over previous
//
#include <hip/hip_runtime.h>
#include <stdint.h>

#define NB 8
#define NT 2048
#define NC 1024
#define HD 64

typedef __attribute__((ext_vector_type(8)))  short s16x8;
typedef __attribute__((ext_vector_type(4)))  float f32x4;
typedef __attribute__((ext_vector_type(16))) float f32x16;

__device__ inline ushort f2b(float f) {
    union { float f; uint32_t u; } c; c.f = f;
    uint32_t u = c.u;
    uint32_t r = (u + 0x7fffu + ((u >> 16) & 1u)) >> 16;   // RNE, finite inputs
    return (ushort)r;
}

__device__ inline uint32_t cvt_pk_bf16(float lo, float hi) {
    uint32_t r;
    asm("v_cvt_pk_bf16_f32 %0, %1, %2" : "=v"(r) : "v"(lo), "v"(hi));
    return r;
}

__device__ inline void gload_lds16(const void* gsrc, void* lds) {
    __builtin_amdgcn_global_load_lds(
        (const __attribute__((address_space(1))) void*)gsrc,
        (__attribute__((address_space(3))) void*)lds, 16, 0, 0);
}

// ---------------------------------------------------------------------------
// Kernel 0: W [1024][192] f32  ->  Wt [192][1024] bf16, q-cols pre-scaled by
// 0.125 * log2(e) so attention logits are already base-2.
// ---------------------------------------------------------------------------
__global__ __launch_bounds__(256) void wprep(const float* __restrict__ W,
                                             ushort* __restrict__ wt) {
    int tid = blockIdx.x * 256 + threadIdx.x;   // 192*1024 total
    int n = tid >> 10;          // 0..191 (output col of qkv)
    int k = tid & 1023;         // 0..1023
    float v = W[k * 192 + n];
    if (n < 64) v *= 0.125f * 1.4426950408889634f;
    wt[n * 1024 + k] = f2b(v);
}

// ---------------------------------------------------------------------------
// Kernel 1: qkv = x @ W.  BM=32, grid 512 (2 blocks/CU), 4 waves.
// global_load_lds(16B) staging of x (f32, swizzled) + W (bf16, swizzled),
// 4 LDS buffers, depth-3 prefetch, counted vmcnt(8) + raw s_barrier
// (never vmcnt(0) in the main loop). ds_reads use the matching XOR swizzle
// -> ~2-way residual bank conflicts (free). A converted f32->bf16 on read.
// Each wave computes 2 m-frags x 3 n-frags (cols (wv*3..wv*3+2)*16).
// ---------------------------------------------------------------------------
__global__ __launch_bounds__(256, 2) void qkv_gemm(const float* __restrict__ x,
                                                   const ushort* __restrict__ wt,
                                                   ushort* __restrict__ qs,
                                                   ushort* __restrict__ kk,
                                                   ushort* __restrict__ vt) {
    __shared__ __align__(16) float  Al[4][1024];   // 4 x 4KB:  [32 rows][32 f32] swizzled
    __shared__ __align__(16) ushort Wl[4][6144];   // 4 x 12KB: [192 rows][32 bf16] swizzled

    const int tid = threadIdx.x;
    const int wv  = tid >> 6;
    const int ls  = tid & 63;
    const int r16 = ls & 15;
    const int hi4 = ls >> 4;          // 0..3
    const int row0 = blockIdx.x * 32;

    // ---- staging source addresses (per-lane, pre-swizzled global) ----
    // A: wave wv stages rows [wv*8, wv*8+8) of the 32-row tile, 1KB linear.
    //    LDS layout read-swizzle: phys = logical ^ ((r&3)<<5) ^ (((r>>2)&1)<<4)
    const int acb = ((ls & 7) * 16) ^ (((ls >> 3) & 3) << 5) ^ (((ls >> 5) & 1) << 4);
    const float* xsrc = x + (size_t)(row0 + wv * 8 + (ls >> 3)) * NC + (acb >> 2);
    // W: wave wv stages row-chunks c = wv*3+j (16 rows x 64B each, 1KB linear).
    //    read-swizzle: phys chunk = hi4 ^ ((n>>1)&3)
    const int wkc = (ls & 3) ^ ((ls >> 3) & 3);
    const ushort* wsrc[3];
#pragma unroll
    for (int j = 0; j < 3; ++j) {
        int c = wv * 3 + j;
        wsrc[j] = wt + (size_t)(c * 16 + (ls >> 2)) * 1024 + wkc * 8;
    }

    // ---- ds_read offsets (bytes, constant across K-steps) ----
    int aoff[2];
#pragma unroll
    for (int m = 0; m < 2; ++m) {
        int r = m * 16 + r16;
        aoff[m] = r * 128 + ((hi4 ^ (r & 3)) << 5) + (((r >> 2) & 1) << 4);
    }
    int boff[3];
#pragma unroll
    for (int nf = 0; nf < 3; ++nf) {
        int n = (wv * 3 + nf) * 16 + r16;
        boff[nf] = n * 64 + ((hi4 ^ ((n >> 1) & 3)) << 4);
    }

    f32x4 acc[2][3];
#pragma unroll
    for (int i = 0; i < 2; ++i)
#pragma unroll
        for (int j = 0; j < 3; ++j)
#pragma unroll
            for (int e = 0; e < 4; ++e) acc[i][j][e] = 0.f;

    auto STAGE = [&](int t) {
        int bb = t & 3;
        gload_lds16(xsrc + t * 32, &Al[bb][wv * 256]);
#pragma unroll
        for (int j = 0; j < 3; ++j)
            gload_lds16(wsrc[j] + t * 32, &Wl[bb][(wv * 3 + j) * 512]);
    };

    auto COMPUTE = [&](int bb) {
        s16x8 af[2], bf[3];
#pragma unroll
        for (int m = 0; m < 2; ++m) {
            float4 a0 = *(const float4*)((const char*)&Al[bb][0] + aoff[m]);
            float4 a1 = *(const float4*)((const char*)&Al[bb][0] + (aoff[m] ^ 16));
            union { uint32_t w[4]; s16x8 v; } pk;
            pk.w[0] = cvt_pk_bf16(a0.x, a0.y);
            pk.w[1] = cvt_pk_bf16(a0.z, a0.w);
            pk.w[2] = cvt_pk_bf16(a1.x, a1.y);
            pk.w[3] = cvt_pk_bf16(a1.z, a1.w);
            af[m] = pk.v;
        }
#pragma unroll
        for (int nf = 0; nf < 3; ++nf)
            bf[nf] = *(const s16x8*)((const char*)&Wl[bb][0] + boff[nf]);
#pragma unroll
        for (int m = 0; m < 2; ++m)
#pragma unroll
            for (int nf = 0; nf < 3; ++nf)
                acc[m][nf] = __builtin_amdgcn_mfma_f32_16x16x32_bf16(
                    af[m], bf[nf], acc[m][nf], 0, 0, 0);
    };

    // ---- prologue: stage steps 0..2 ----
    STAGE(0); STAGE(1); STAGE(2);

    // ---- main loop: wait(own stage t) -> barrier -> stage t+3 -> compute t
    for (int t = 0; t < 29; ++t) {
        asm volatile("s_waitcnt vmcnt(8)" ::: "memory");
        __builtin_amdgcn_s_barrier();
        __builtin_amdgcn_sched_barrier(0);
        STAGE(t + 3);
        COMPUTE(t & 3);
    }
    // t = 29, 30, 31: drain 8 -> 4 -> 0
    asm volatile("s_waitcnt vmcnt(8)" ::: "memory");
    __builtin_amdgcn_s_barrier();
    __builtin_amdgcn_sched_barrier(0);
    COMPUTE(29 & 3);
    asm volatile("s_waitcnt vmcnt(4)" ::: "memory");
    __builtin_amdgcn_s_barrier();
    __builtin_amdgcn_sched_barrier(0);
    COMPUTE(30 & 3);
    asm volatile("s_waitcnt vmcnt(0)" ::: "memory");
    __builtin_amdgcn_s_barrier();
    __builtin_amdgcn_sched_barrier(0);
    COMPUTE(31 & 3);

    // ---- epilogue: scatter to qs / kk / vt(bf16, transposed) ----
    const int b = row0 >> 11;
#pragma unroll
    for (int m = 0; m < 2; ++m) {
        const int rbase = row0 + m * 16 + hi4 * 4;
#pragma unroll
        for (int nf = 0; nf < 3; ++nf) {
            int nfg = wv * 3 + nf;             // absolute 16-col fragment
            int colg = nfg * 16 + r16;         // 0..191
            f32x4 v = acc[m][nf];
            if (nfg < 4) {
#pragma unroll
                for (int j = 0; j < 4; ++j)
                    qs[(size_t)(rbase + j) * HD + colg] = f2b(v[j]);
            } else if (nfg < 8) {
#pragma unroll
                for (int j = 0; j < 4; ++j)
                    kk[(size_t)(rbase + j) * HD + (colg - 64)] = f2b(v[j]);
            } else {
                int d = colg - 128;
                union { ushort4 s; ushort u[4]; } pk;
#pragma unroll
                for (int j = 0; j < 4; ++j) pk.u[j] = f2b(v[j]);
                *(ushort4*)(&vt[((size_t)(b * 64 + d)) * NT + (rbase & (NT - 1))]) = pk.s;
            }
        }
    }
}

// ---------------------------------------------------------------------------
// Kernel 2: causal flash attention. 4 waves/block, intra-block split-K:
// wave w handles k-tiles w, w+4, ... of its 32-row q-tile; partial
// (m,l,o) merged in LDS with exp2 rescaling. grid = 512, big tiles first.
// ---------------------------------------------------------------------------
__global__ __launch_bounds__(256) void attn(const ushort* __restrict__ qs,
                                            const ushort* __restrict__ kk,
                                            const ushort* __restrict__ vt,
                                            float* __restrict__ out) {
    __shared__ float ob[4][64][33];   // per-wave unnormalized O^T partials
    __shared__ float ml[4][2][32];    // per-wave m / lsum per q col

    const int bid  = blockIdx.x;
    const int b    = bid & 7;
    const int tile = 63 - (bid >> 3);          // big-first for balance
    const int tid  = threadIdx.x;
    const int wv   = tid >> 6;                 // 0..3  (k-split index)
    const int l    = tid & 63;
    const int qcol = l & 31;
    const int hi   = l >> 5;
    const int r0   = tile * 32;

    const ushort* qb = qs + ((size_t)(b * NT + r0)) * HD;
    const ushort* kb = kk + (size_t)b * NT * HD;
    const ushort* vb = vt + (size_t)b * HD * NT;

    s16x8 qf[4];
#pragma unroll
    for (int c = 0; c < 4; ++c)
        qf[c] = *(const s16x8*)(qb + (size_t)qcol * HD + c * 16 + hi * 8);

    f32x16 o0, o1;
#pragma unroll
    for (int i = 0; i < 16; ++i) { o0[i] = 0.f; o1[i] = 0.f; }
    float m = -3.0e30f, lsum = 0.f;

    if (wv <= tile) {
        s16x8 kf[4], vf[4];
        {
            const ushort* kr = kb + (size_t)(wv * 32 + qcol) * HD;
#pragma unroll
            for (int c = 0; c < 4; ++c)
                kf[c] = *(const s16x8*)(kr + c * 16 + hi * 8);
#pragma unroll
            for (int dt = 0; dt < 2; ++dt)
#pragma unroll
                for (int kc = 0; kc < 2; ++kc)
                    vf[dt * 2 + kc] = *(const s16x8*)(vb + (size_t)(dt * 32 + qcol) * NT
                                                      + wv * 32 + kc * 16 + hi * 8);
        }

        for (int kt = wv; kt <= tile; kt += 4) {
            // S^T = K . Q^T   (col = q, row-regs = k_local)
            f32x16 s;
#pragma unroll
            for (int i = 0; i < 16; ++i) s[i] = 0.f;
#pragma unroll
            for (int c = 0; c < 4; ++c)
                s = __builtin_amdgcn_mfma_f32_32x32x16_bf16(kf[c], qf[c], s, 0, 0, 0);

            // prefetch this wave's next K/V tiles (stride 4)
            s16x8 kfn[4], vfn[4];
            const bool more = (kt + 4 <= tile);
            if (more) {
                const ushort* kr = kb + (size_t)((kt + 4) * 32 + qcol) * HD;
#pragma unroll
                for (int c = 0; c < 4; ++c)
                    kfn[c] = *(const s16x8*)(kr + c * 16 + hi * 8);
#pragma unroll
                for (int dt = 0; dt < 2; ++dt)
#pragma unroll
                    for (int kc = 0; kc < 2; ++kc)
                        vfn[dt * 2 + kc] = *(const s16x8*)(vb + (size_t)(dt * 32 + qcol) * NT
                                                           + (kt + 4) * 32 + kc * 16 + hi * 8);
            }

            // online softmax (per-lane scalar state: one q per lane)
            const bool diag = (kt == tile);
            float p[16];
#pragma unroll
            for (int r = 0; r < 16; ++r) {
                int klocal = (r & 3) + 8 * (r >> 2) + 4 * hi;
                float sv = s[r];
                if (diag && klocal > qcol) sv = -3.0e30f;
                p[r] = sv;
            }
            float pmax = p[0];
#pragma unroll
            for (int r = 1; r < 16; ++r) pmax = fmaxf(pmax, p[r]);
            pmax = fmaxf(pmax, __shfl_xor(pmax, 32));
            float mnew = fmaxf(m, pmax);
            float corr = exp2f(m - mnew);
            m = mnew;
            float rs = 0.f;
#pragma unroll
            for (int r = 0; r < 16; ++r) { p[r] = exp2f(p[r] - mnew); rs += p[r]; }
            rs += __shfl_xor(rs, 32);
            lsum = lsum * corr + rs;
#pragma unroll
            for (int i = 0; i < 16; ++i) { o0[i] *= corr; o1[i] *= corr; }

            // P (f32, S^T layout) -> bf16 B-fragments via cvt_pk + lane^32 exchange
#pragma unroll
            for (int kc = 0; kc < 2; ++kc) {
                int pb = kc * 8;
                uint32_t a0 = cvt_pk_bf16(p[pb + 0], p[pb + 1]);
                uint32_t a1 = cvt_pk_bf16(p[pb + 2], p[pb + 3]);
                uint32_t b0 = cvt_pk_bf16(p[pb + 4], p[pb + 5]);
                uint32_t b1 = cvt_pk_bf16(p[pb + 6], p[pb + 7]);
                uint32_t a0x = __shfl_xor(a0, 32);
                uint32_t a1x = __shfl_xor(a1, 32);
                uint32_t b0x = __shfl_xor(b0, 32);
                uint32_t b1x = __shfl_xor(b1, 32);
                union { uint32_t w[4]; s16x8 v; } frag;
                frag.w[0] = hi ? b0x : a0;
                frag.w[1] = hi ? b1x : a1;
                frag.w[2] = hi ? b0  : a0x;
                frag.w[3] = hi ? b1  : a1x;
                o0 = __builtin_amdgcn_mfma_f32_32x32x16_bf16(vf[0 * 2 + kc], frag.v, o0, 0, 0, 0);
                o1 = __builtin_amdgcn_mfma_f32_32x32x16_bf16(vf[1 * 2 + kc], frag.v, o1, 0, 0, 0);
            }

            if (more) {
#pragma unroll
                for (int c = 0; c < 4; ++c) kf[c] = kfn[c];
#pragma unroll
                for (int c = 0; c < 4; ++c) vf[c] = vfn[c];
            }
        }
    }

    // --- write per-wave partials (unnormalized) ---
#pragma unroll
    for (int r = 0; r < 16; ++r) {
        int d = (r & 3) + 8 * (r >> 2) + 4 * hi;
        ob[wv][d][qcol]      = o0[r];
        ob[wv][d + 32][qcol] = o1[r];
    }
    if (hi == 0) {
        ml[wv][0][qcol] = m;
        ml[wv][1][qcol] = lsum;
    }
    __syncthreads();

    // --- merge 4 partials + coalesced f32 store ---
    // thread -> (q = tid>>3, d block of 8 at (tid&7)*8)
    const int q  = tid >> 3;
    const int j0 = (tid & 7) * 8;
    float mw[4];
#pragma unroll
    for (int w = 0; w < 4; ++w) mw[w] = ml[w][0][q];
    float M = fmaxf(fmaxf(mw[0], mw[1]), fmaxf(mw[2], mw[3]));
    float sw[4]; float L = 0.f;
#pragma unroll
    for (int w = 0; w < 4; ++w) {
        sw[w] = exp2f(mw[w] - M);
        L += sw[w] * ml[w][1][q];
    }
    float invL = 1.0f / L;
    float vals[8];
#pragma unroll
    for (int j = 0; j < 8; ++j) {
        int d = j0 + j;
        float acc = 0.f;
#pragma unroll
        for (int w = 0; w < 4; ++w) acc += sw[w] * ob[w][d][q];
        vals[j] = acc * invL;
    }
    float* orow = out + ((size_t)(b * NT + r0 + q)) * HD + j0;
    *(float4*)(orow)     = make_float4(vals[0], vals[1], vals[2], vals[3]);
    *(float4*)(orow + 4) = make_float4(vals[4], vals[5], vals[6], vals[7]);
}

// ---------------------------------------------------------------------------
extern "C" void kernel_launch(void* const* d_in, const int* in_sizes, int n_in,
                              void* d_out, int out_size, void* d_ws, size_t ws_size,
                              hipStream_t stream) {
    const float* x = (const float*)d_in[0];
    const float* W = (const float*)d_in[1];
    float* out = (float*)d_out;

    ushort* qs = (ushort*)d_ws;                 // [8][2048][64] bf16 (pre-scaled q)
    ushort* kk = qs + (size_t)NB * NT * HD;     // [8][2048][64]
    ushort* vt = kk + (size_t)NB * NT * HD;     // [8][64][2048]  (V transposed)
    ushort* wt = vt + (size_t)NB * NT * HD;     // [192][1024]    (W^T bf16)

    wprep<<<768, 256, 0, stream>>>(W, wt);
    qkv_gemm<<<512, 256, 0, stream>>>(x, wt, qs, kk, vt);
    attn<<<512, 256, 0, stream>>>(qs, kk, vt, out);
}